// Round 5
// baseline (58.816 us; speedup 1.0000x reference)
//
#include <hip/hip_runtime.h>
#include <math.h>

#define BB 8
#define TT 128
#define U1 65
#define UU 64
#define VV 1024
#define CSTR 130            // comb row stride (pairs)
#define COMB_N 8456         // 65*130 pairs + 6 pad (prefetch overrun headroom)
#define NEGINF -1e30f
#define LOG2E 1.4426950408889634f
#define LN2   0.6931471805599453f

typedef float vf4 __attribute__((ext_vector_type(4)));   // nontemporal-builtin-compatible

// shfl_up by 1 via DPP wave_shr:1 (HW-verified in rounds 2-3)
__device__ __forceinline__ float shfl_up1(float x) {
  return __int_as_float(__builtin_amdgcn_update_dpp(
      0, __float_as_int(x), 0x138, 0xf, 0xf, false));
}

// log-add-exp in log2 domain: native v_exp_f32 / v_log_f32
__device__ __forceinline__ float lae2(float a, float b) {
  const float mx = fmaxf(a, b);
  const float nd = fminf(a - b, b - a);     // -|a-b|
  return mx + log2f(1.f + exp2f(nd));
}

// ---------------- Kernel 1: logsumexp + fused comb-layout emit ---------------
// comb[b][u][t] = ( blank'[t-1][u], label'[t][u-1] ) in log2 scale.
// All comb stores NONTEMPORAL: keep lines out of producer-XCD L2 so the DP
// kernel's staging reads don't hit remote dirty lines.
__global__ __launch_bounds__(256) void lse_gather(
    const float* __restrict__ logits, const int* __restrict__ y,
    const int* __restrict__ logit_lens, const int* __restrict__ y_lens,
    float* __restrict__ comb, int* __restrict__ done) {
  if (blockIdx.x == 0 && threadIdx.x == 0) *done = 0;   // reset ticket for kernel 2

  const int wave = threadIdx.x >> 6;
  const int lane = threadIdx.x & 63;
  const int row  = blockIdx.x * 4 + wave;          // row in [0, B*T*U1)
  const int u  = row % U1;
  const int bt = row / U1;
  const int b  = bt / TT;
  const int t  = bt % TT;

  float* cb = comb + (size_t)b * COMB_N * 2;

  // structural padding — writers are never-skipped waves (t=0, u=0 always valid)
  if (lane == 0) {
    if (t == 0) __builtin_nontemporal_store(NEGINF, &cb[2 * (u * CSTR) + 0]);
    if (u == 0) __builtin_nontemporal_store(NEGINF, &cb[2 * t + 1]);
  }
  if (t >= logit_lens[b] || u > y_lens[b]) return;   // row not on any result path

  const float4* rp = (const float4*)(logits + (size_t)row * VV);
  float4 x0 = rp[lane];
  float4 x1 = rp[lane + 64];
  float4 x2 = rp[lane + 128];
  float4 x3 = rp[lane + 192];

  const bool have_label = (u < UU);
  float lab_logit = 0.f;
  if (have_label && lane == 0)
    lab_logit = logits[(size_t)row * VV + y[b * UU + u]];  // L1/L2 hit

  float m = fmaxf(fmaxf(fmaxf(x0.x, x0.y), fmaxf(x0.z, x0.w)),
                  fmaxf(fmaxf(x1.x, x1.y), fmaxf(x1.z, x1.w)));
  m = fmaxf(m, fmaxf(fmaxf(fmaxf(x2.x, x2.y), fmaxf(x2.z, x2.w)),
                     fmaxf(fmaxf(x3.x, x3.y), fmaxf(x3.z, x3.w))));
#pragma unroll
  for (int s = 32; s >= 1; s >>= 1) m = fmaxf(m, __shfl_xor(m, s));

  float ss = __expf(x0.x - m) + __expf(x0.y - m) + __expf(x0.z - m) + __expf(x0.w - m)
           + __expf(x1.x - m) + __expf(x1.y - m) + __expf(x1.z - m) + __expf(x1.w - m)
           + __expf(x2.x - m) + __expf(x2.y - m) + __expf(x2.z - m) + __expf(x2.w - m)
           + __expf(x3.x - m) + __expf(x3.y - m) + __expf(x3.z - m) + __expf(x3.w - m);
#pragma unroll
  for (int s = 32; s >= 1; s >>= 1) ss += __shfl_xor(ss, s);

  if (lane == 0) {
    const float lse = m + __logf(ss);
    __builtin_nontemporal_store((x0.x - lse) * LOG2E,
                                &cb[2 * (u * CSTR + t + 1) + 0]);      // blank
    if (have_label)
      __builtin_nontemporal_store((lab_logit - lse) * LOG2E,
                                  &cb[2 * ((u + 1) * CSTR + t) + 1]);  // label
  }
}

// ---------------- Kernel 2: anti-diagonal alpha DP + fused finalize ----------
__global__ __launch_bounds__(256) void alpha_dp(
    const float2* __restrict__ comb, const int* __restrict__ logit_lens,
    const int* __restrict__ y_lens, float* __restrict__ losses,
    int* __restrict__ done, float* __restrict__ out) {
  const int b = blockIdx.x;
  const int tid = threadIdx.x;

  __shared__ __align__(16) float2 cs[COMB_N];
  {
    const vf4* g = (const vf4*)(comb + (size_t)b * COMB_N);
    vf4* s = (vf4*)cs;
    for (int i = tid; i < COMB_N / 2; i += 256)
      s[i] = __builtin_nontemporal_load(&g[i]);
  }
  __syncthreads();
  if (tid >= 64) return;
  const int lane = tid;

  const int tEnd = logit_lens[b] - 1;   // in [63,127]
  const int uEnd = y_lens[b];           // in [32,64]
  const int dT   = tEnd + uEnd;         // >= 95

  const float2* cp   = cs + 129 * lane; // cp[d] = comb[u][d-u]
  const float2* cp64 = cs + 8256;       // cp64[d] = comb[64][d-64] (broadcast)

  float A   = (lane == 0) ? 0.f : NEGINF;
  float A64 = NEGINF;

#define STEP(cc, ee)                                      \
  {                                                       \
    const float aleft = shfl_up1(A);                      \
    const float top   = A + (cc).x;                       \
    const float lft   = aleft + (cc).y;                   \
    const float xt    = A64 + (ee).x;                     \
    const float xl    = A + (ee).y;   /* pre-update A */  \
    A   = lae2(top, lft);                                 \
    A64 = lae2(xt, xl);                                   \
  }

  float2 c0 = cp[1], c1 = cp[2], c2 = cp[3], c3 = cp[4];
  float2 e0 = cp64[1], e1 = cp64[2], e2 = cp64[3], e3 = cp64[4];

  int d = 1;
  for (; d + 3 <= dT; d += 4) {
    const float2 n0 = cp[d + 4], n1 = cp[d + 5], n2 = cp[d + 6], n3 = cp[d + 7];
    const float2 f0 = cp64[d + 4], f1 = cp64[d + 5], f2 = cp64[d + 6], f3 = cp64[d + 7];
    STEP(c0, e0) STEP(c1, e1) STEP(c2, e2) STEP(c3, e3)
    c0 = n0; c1 = n1; c2 = n2; c3 = n3;
    e0 = f0; e1 = f1; e2 = f2; e3 = f3;
  }
  for (; d <= dT; ++d) {
    const float2 c = cp[d], e = cp64[d];
    STEP(c, e)
  }
#undef STEP

  float res = 0.f;
  bool have = false;
  if (uEnd == 64) {
    if (lane == 63) { res = A64 + cs[64 * CSTR + tEnd + 1].x; have = true; }
  } else if (lane == uEnd) {
    res = A + cs[uEnd * CSTR + tEnd + 1].x; have = true;
  }

  if (have) {
    const float loss = -res * LN2;
    __hip_atomic_store(&losses[b], loss, __ATOMIC_RELEASE, __HIP_MEMORY_SCOPE_AGENT);
    const int tk = __hip_atomic_fetch_add(done, 1, __ATOMIC_ACQ_REL, __HIP_MEMORY_SCOPE_AGENT);
    if (tk == BB - 1) {            // last block finalizes: deterministic mean
      float s = 0.f;
#pragma unroll
      for (int i = 0; i < BB; ++i)
        s += __hip_atomic_load(&losses[i], __ATOMIC_ACQUIRE, __HIP_MEMORY_SCOPE_AGENT);
      out[0] = s * (1.f / BB);
    }
  }
}

extern "C" void kernel_launch(void* const* d_in, const int* in_sizes, int n_in,
                              void* d_out, int out_size, void* d_ws, size_t ws_size,
                              hipStream_t stream) {
  const float* logits     = (const float*)d_in[0];
  const int*   logit_lens = (const int*)d_in[1];
  const int*   y          = (const int*)d_in[2];
  const int*   y_lens     = (const int*)d_in[3];
  float* out = (float*)d_out;

  float2* comb  = (float2*)d_ws;                        // BB * COMB_N pairs
  float*  losses = (float*)(comb + (size_t)BB * COMB_N);
  int*    done   = (int*)(losses + BB);

  const int rows = BB * TT * U1;                        // 66560
  lse_gather<<<rows / 4, 256, 0, stream>>>(logits, y, logit_lens, y_lens,
                                           (float*)comb, done);
  alpha_dp<<<BB, 256, 0, stream>>>(comb, logit_lens, y_lens, losses, done, out);
}